// Round 11
// baseline (560.862 us; speedup 1.0000x reference)
//
#include <hip/hip_runtime.h>
#include <hip/hip_bf16.h>
#include <math.h>

#define M_BATCH   4096
#define K_IN      4096
#define N_OUT     4096
#define NELEM     16777216   // 4096*4096

typedef __bf16 bf16;
typedef bf16  bf16x8 __attribute__((ext_vector_type(8)));
typedef float f32x4  __attribute__((ext_vector_type(4)));
typedef float f32x16 __attribute__((ext_vector_type(16)));
typedef unsigned short u16;
typedef u16 u16x8 __attribute__((ext_vector_type(8)));

// fast softplus: hardware v_exp/v_log, poly for small e (w_sigma in [-12,-2.2])
__device__ __forceinline__ float softplus_fast(float x) {
    if (x > 15.f) return x;
    const float e = __expf(x);
    if (e < 0.0883f)  // log1p(e) = e - e^2/2 + e^3/3, trunc err < 2e-6 rel
        return e * (1.f + e * (-0.5f + e * 0.3333333f));
    return __logf(1.f + e);
}

__device__ __forceinline__ unsigned short f2bf_bits(float x) {
    bf16 b = (bf16)x;
    return __builtin_bit_cast(unsigned short, b);
}

// async global->LDS, 16B per lane. LDS dst must be wave-uniform base + lane*16.
__device__ __forceinline__ void gload_lds16(const void* g, void* l) {
    __builtin_amdgcn_global_load_lds(
        (__attribute__((address_space(1))) void*)g,
        (__attribute__((address_space(3))) void*)l,
        16, 0, 0);
}

// ---------------------------------------------------------------------------
// prep_all v2 (R6): ONE launch.
//   bid <  2048 : prep_w — 128(i) x 64(o) tiles, 256B-contiguous transposed
//                 stores, 16B/lane; KL partials via shfl_xor wave-reduce.
//   bid >= 2048 : prep_a — mu -> A, A2=mu^2 (bf16), 8 elems/thread, 16B stores.
// ---------------------------------------------------------------------------
__global__ __launch_bounds__(256) void prep_all(const float* __restrict__ wmu,
                                                const float* __restrict__ wsg,
                                                bf16* __restrict__ Wmu_t,
                                                bf16* __restrict__ Wsg_t,
                                                float* __restrict__ partials,
                                                const float4* __restrict__ mu,
                                                u16x8* __restrict__ A8,
                                                u16x8* __restrict__ A28) {
    __shared__ bf16 tmu[128][65];
    __shared__ bf16 tsg[128][65];
    __shared__ float wred[4][3];

    const int t   = threadIdx.x;
    const int bid = blockIdx.x;

    if (bid >= 2048) {                       // ---- prep_a part ----
        const int i = (bid - 2048) * 256 + t;        // u16x8-granule index
        const float4 v0 = mu[2 * i];
        const float4 v1 = mu[2 * i + 1];
        u16x8 a, a2;
        a[0] = f2bf_bits(v0.x); a[1] = f2bf_bits(v0.y);
        a[2] = f2bf_bits(v0.z); a[3] = f2bf_bits(v0.w);
        a[4] = f2bf_bits(v1.x); a[5] = f2bf_bits(v1.y);
        a[6] = f2bf_bits(v1.z); a[7] = f2bf_bits(v1.w);
        a2[0] = f2bf_bits(v0.x * v0.x); a2[1] = f2bf_bits(v0.y * v0.y);
        a2[2] = f2bf_bits(v0.z * v0.z); a2[3] = f2bf_bits(v0.w * v0.w);
        a2[4] = f2bf_bits(v1.x * v1.x); a2[5] = f2bf_bits(v1.y * v1.y);
        a2[6] = f2bf_bits(v1.z * v1.z); a2[7] = f2bf_bits(v1.w * v1.w);
        A8[i]  = a;
        A28[i] = a2;
        return;
    }

    // ---- prep_w part: 128(i) x 64(o) tile ----
    const int ti = bid >> 6;            // i (K) tile, 0..31  (128 rows each)
    const int tj = bid & 63;            // o (N) tile, 0..63  (64 cols each)
    const int r  = t >> 4;              // 0..15
    const int c4 = (t & 15) << 2;       // 0,4,..,60

    float s_abs = 0.f, s_sp = 0.f, s_log = 0.f;

    for (int rr = 0; rr < 128; rr += 16) {
        const int row = rr + r;
        const size_t goff = (size_t)(ti * 128 + row) * N_OUT + tj * 64 + c4;
        const float4 vm = *(const float4*)(wmu + goff);
        const float4 vs = *(const float4*)(wsg + goff);
        const float sp0 = softplus_fast(vs.x), sp1 = softplus_fast(vs.y);
        const float sp2 = softplus_fast(vs.z), sp3 = softplus_fast(vs.w);
        s_abs += fabsf(vm.x) + fabsf(vm.y) + fabsf(vm.z) + fabsf(vm.w);
        s_sp  += sp0 + sp1 + sp2 + sp3;
        s_log += __logf(sp0) + __logf(sp1) + __logf(sp2) + __logf(sp3);
        tmu[row][c4 + 0] = (bf16)vm.x; tmu[row][c4 + 1] = (bf16)vm.y;
        tmu[row][c4 + 2] = (bf16)vm.z; tmu[row][c4 + 3] = (bf16)vm.w;
        tsg[row][c4 + 0] = (bf16)sp0;  tsg[row][c4 + 1] = (bf16)sp1;
        tsg[row][c4 + 2] = (bf16)sp2;  tsg[row][c4 + 3] = (bf16)sp3;
    }
    __syncthreads();

    // transposed write: Wt[o][i] = tile[i][o]; 16 threads x 16 B = 256 B/row
#pragma unroll
    for (int p = 0; p < 4; ++p) {
        const int jj = p * 16 + (t >> 4);   // o within tile
        const int i0 = (t & 15) << 3;       // i chunk (8 elems)
        u16x8 om, os;
#pragma unroll
        for (int e = 0; e < 8; ++e) {
            om[e] = __builtin_bit_cast(unsigned short, tmu[i0 + e][jj]);
            os[e] = __builtin_bit_cast(unsigned short, tsg[i0 + e][jj]);
        }
        const size_t o = (size_t)(tj * 64 + jj) * K_IN + ti * 128 + i0;
        *(u16x8*)(Wmu_t + o) = om;
        *(u16x8*)(Wsg_t + o) = os;
    }

    // KL partials: shfl_xor wave-reduce, one LDS combine
    float v0 = s_log, v1 = s_sp, v2 = s_abs;
#pragma unroll
    for (int off = 32; off; off >>= 1) {
        v0 += __shfl_xor(v0, off, 64);
        v1 += __shfl_xor(v1, off, 64);
        v2 += __shfl_xor(v2, off, 64);
    }
    if ((t & 63) == 0) {
        wred[t >> 6][0] = v0; wred[t >> 6][1] = v1; wred[t >> 6][2] = v2;
    }
    __syncthreads();
    if (t == 0) {
        partials[0 * 2048 + bid] = wred[0][0] + wred[1][0] + wred[2][0] + wred[3][0];
        partials[1 * 2048 + bid] = wred[0][1] + wred[1][1] + wred[2][1] + wred[3][1];
        partials[2 * 2048 + bid] = wred[0][2] + wred[1][2] + wred[2][2] + wred[3][2];
    }
}

// ---------------------------------------------------------------------------
// gemm_bf16: C[M,N] = A[M,K](bf16) * Bt[N,K]^T(bf16) + bias  (fp32 out)
// FINAL = exact R6 configuration (best verified: gemm 258us, absmax 0.25,
// total 556.7us). R10's k-slice variant is REVERTED: it extended B-par
// read lifetime into the B-restage phases -> WAR race (absmax 7.75).
// Structure: 256x256 tile, BK=64, 8 waves (2M x 4N, 128x64/wave), 128 KiB
// dbuf LDS, 32x32x16 MFMA, flat [par][256][64] layout + 16B-chunk XOR
// swizzle (linear gload_lds dst + inverse-swizzled src, rule 21).
// Phase q = m-fragment q: 4 A ds_read_b128 (+8 B bulk at q0 — all B-par
// reads complete in phase 1, PROVING the ph3/4 B-restage WAR safe via the
// end-ph2 barrier). R4 4-barrier skeleton: end-ph2/ph6 plain barrier,
// end-ph4/ph8 vmcnt(4)+barrier (counted: retires prev K-tile's 8 loads,
// keeps the 4 just-issued in flight). XCD 4x8 remap (FETCH -33%, R2).
// Session ledger (measured): R2 read-ahead -16%; R3 reorder 0; R4 barrier
// cut +4%; R5 32x32 +3%; R7 conflict-layout 0 (SQ_LDS_BANK_CONFLICT is
// proportional to ds_read_b128 count — intrinsic, not fixable); R8 4-wave
// occupancy -68% (LDS-traffic-bound); R9 B-in-reg -43% (L2-scatter).
// ---------------------------------------------------------------------------
#define MFMA32 __builtin_amdgcn_mfma_f32_32x32x16_bf16

__global__ __launch_bounds__(512, 2) void gemm_bf16(
    const bf16* __restrict__ A1,  const bf16* __restrict__ Bt1,
    const float* __restrict__ bias1, float* __restrict__ C1,
    const bf16* __restrict__ A2_, const bf16* __restrict__ Bt2,
    const float* __restrict__ bias2, float* __restrict__ C2) {

    __shared__ bf16 As[2 * 256 * 64];   // [par][row 256][k 64], 64 KiB
    __shared__ bf16 Bs[2 * 256 * 64];   // 64 KiB

    const int z = blockIdx.z;
    const bf16*  A    = z ? A2_   : A1;
    const bf16*  Bt   = z ? Bt2   : Bt1;
    const float* bias = z ? bias2 : bias1;
    float*       C    = z ? C2    : C1;

    const int t = threadIdx.x;
    // XCD-aware remap: each XCD gets a contiguous 4x8 block of the tile grid.
    const int id   = blockIdx.y * 16 + blockIdx.x;  // 0..255 per z-slice
    const int xcd  = id & 7, cc_ = id >> 3;
    const int rowBase = (((xcd >> 1) << 2) + (cc_ >> 3)) << 8;
    const int colBase = (((xcd & 1) << 3) + (cc_ & 7)) << 8;

    // ---- staging: gload_lds writes linear (t*16); source chunk
    // inverse-swizzled so reads can swizzle (rule 21).
    const int srow   = t >> 3;                  // 0..63 (row within 64-row slab)
    const int schunk = (t & 7) ^ (srow & 7);    // source 16B chunk within row
    const char* aG = (const char*)(A  + (size_t)(rowBase + srow) * K_IN + schunk * 8);
    const char* bG = (const char*)(Bt + (size_t)(colBase + srow) * K_IN + schunk * 8);
    char* aL = (char*)As + t * 16;
    char* bL = (char*)Bs + t * 16;

#define STAGE_A(kt, h, par) do {                                               \
        const size_t kb_ = (size_t)((kt) & 63) << 7;                           \
        gload_lds16(aG + kb_ + (size_t)(h) * (128 * K_IN * 2),                 \
                    aL + ((par) << 15) + ((h) << 14));                         \
        gload_lds16(aG + kb_ + (size_t)(h) * (128 * K_IN * 2) + 64 * K_IN * 2, \
                    aL + ((par) << 15) + ((h) << 14) + 8192);                  \
    } while (0)
#define STAGE_B(kt, h, par) do {                                               \
        const size_t kb_ = (size_t)((kt) & 63) << 7;                           \
        gload_lds16(bG + kb_ + (size_t)(h) * (128 * K_IN * 2),                 \
                    bL + ((par) << 15) + ((h) << 14));                         \
        gload_lds16(bG + kb_ + (size_t)(h) * (128 * K_IN * 2) + 64 * K_IN * 2, \
                    bL + ((par) << 15) + ((h) << 14) + 8192);                  \
    } while (0)

    // ---- fragment read addressing (32x32x16, flat 128B rows) ----
    const int lane = t & 63;
    const int wave = t >> 6;
    const int wr = wave >> 2;            // 0..1 : M half (128 rows)
    const int wc = wave & 3;             // 0..3 : N quarter (64 cols)
    const int fr = lane & 31;            // row within 32-row frag
    const int kh = lane >> 5;            // k-half (8 of 16 k per slice)
    int cS[4];                           // swizzled 16B-chunk byte offsets
#pragma unroll
    for (int s = 0; s < 4; ++s)
        cS[s] = (((s << 1) | kh) ^ (fr & 7)) << 4;
    const char* aRd = (const char*)As + ((wr << 7) + fr) * 128;
    const char* bRd = (const char*)Bs + ((wc << 6) + fr) * 128;

// Phase q = m-fragment q: 4 A ds_read_b128 (+8 B bulk at q0), 8 MFMA
// (2 n-frags x 4 k-slices, per-acc ks order 0..3).
// BAR: 0 = free-run, 1 = barrier after MFMA; VM: vmcnt(4) before barrier.
#define PHASE(par, q, STAGE_STMT, VM, BAR) do {                                \
        if ((q) == 0) {                                                        \
            _Pragma("unroll")                                                  \
            for (int n = 0; n < 2; ++n)                                        \
                _Pragma("unroll")                                              \
                for (int s = 0; s < 4; ++s)                                    \
                    bfrag[n][s] = *(const bf16x8*)(bRd + ((par) << 15)         \
                                                  + (n << 12) + cS[s]);        \
        }                                                                      \
        bf16x8 a_[4];                                                          \
        _Pragma("unroll")                                                      \
        for (int s = 0; s < 4; ++s)                                            \
            a_[s] = *(const bf16x8*)(aRd + ((par) << 15) + ((q) << 12) + cS[s]);\
        STAGE_STMT;                                                            \
        __builtin_amdgcn_s_setprio(1);                                         \
        _Pragma("unroll")                                                      \
        for (int s = 0; s < 4; ++s) {                                          \
            acc[q][0] = MFMA32(a_[s], bfrag[0][s], acc[q][0], 0, 0, 0);        \
            acc[q][1] = MFMA32(a_[s], bfrag[1][s], acc[q][1], 0, 0, 0);        \
        }                                                                      \
        __builtin_amdgcn_s_setprio(0);                                         \
        if (VM) {                                                              \
            asm volatile("s_waitcnt vmcnt(4)" ::: "memory");                   \
            __builtin_amdgcn_sched_barrier(0);                                 \
        }                                                                      \
        if (BAR) {                                                             \
            __builtin_amdgcn_sched_barrier(0);                                 \
            __builtin_amdgcn_s_barrier();                                      \
            __builtin_amdgcn_sched_barrier(0);                                 \
        }                                                                      \
    } while (0)

    f32x16 acc[4][2];
#pragma unroll
    for (int m = 0; m < 4; ++m)
#pragma unroll
        for (int n = 0; n < 2; ++n)
#pragma unroll
            for (int e = 0; e < 16; ++e) acc[m][n][e] = 0.f;

    // prologue: stage kt0 + kt1 fully (16 loads); retire kt0 (keep kt1 in flight)
    STAGE_A(0, 0, 0); STAGE_A(0, 1, 0);
    STAGE_B(0, 0, 0); STAGE_B(0, 1, 0);
    STAGE_A(1, 0, 1); STAGE_A(1, 1, 1);
    STAGE_B(1, 0, 1); STAGE_B(1, 1, 1);
    asm volatile("s_waitcnt vmcnt(8)" ::: "memory");
    __builtin_amdgcn_sched_barrier(0);
    __builtin_amdgcn_s_barrier();
    __builtin_amdgcn_sched_barrier(0);

    for (int i = 0; i < 32; ++i) {          // 2 K-tiles per iter, K = 64*64
        const int kA1 = 2 * i + 1;          // A(kt+1) -> par1 (restage noop i=0)
        const int kB0 = 2 * i + 2;          // B(kt+2) -> par0
        const int kA0 = 2 * i + 2;          // A(kt+2) -> par0
        const int kB1 = 2 * i + 3;          // B(kt+3) -> par1
        {   // phases 1-4: compute kt=2i from par0
            bf16x8 bfrag[2][4];
            PHASE(0, 0, STAGE_A(kA1, 0, 1), 0, 0);
            PHASE(0, 1, STAGE_A(kA1, 1, 1), 0, 1);   // end-ph2 barrier
            PHASE(0, 2, STAGE_B(kB0, 0, 0), 0, 0);
            PHASE(0, 3, STAGE_B(kB0, 1, 0), 1, 1);   // vmcnt(4) + end-ph4 barrier
        }
        {   // phases 5-8: compute kt=2i+1 from par1
            bf16x8 bfrag[2][4];
            PHASE(1, 0, STAGE_A(kA0, 0, 0), 0, 0);
            PHASE(1, 1, STAGE_A(kA0, 1, 0), 0, 1);   // end-ph6 barrier
            PHASE(1, 2, STAGE_B(kB1, 0, 1), 0, 0);
            PHASE(1, 3, STAGE_B(kB1, 1, 1), 1, 1);   // vmcnt(4) + end-ph8 barrier
        }
    }

    asm volatile("s_waitcnt vmcnt(0)" ::: "memory");  // drain tail junk loads

    // epilogue: 32x32 C/D layout col=lane&31, row=(reg&3)+8*(reg>>2)+4*kh
#pragma unroll
    for (int n = 0; n < 2; ++n) {
        const int c = colBase + (wc << 6) + (n << 5) + fr;
        float b = bias[c];
        if (z) b = softplus_fast(b);
#pragma unroll
        for (int m = 0; m < 4; ++m) {
            const int rb = rowBase + (wr << 7) + (m << 5) + (kh << 2);
#pragma unroll
            for (int reg = 0; reg < 16; ++reg) {
                const int row = rb + (reg & 3) + ((reg >> 2) << 3);
                C[(size_t)row * N_OUT + c] = acc[m][n][reg] + b;
            }
        }
    }
#undef STAGE_A
#undef STAGE_B
#undef PHASE
}

// ---------------------------------------------------------------------------
// kl_finish: reduce partials (3 x n) in double, write scalar kl.
// ---------------------------------------------------------------------------
__global__ __launch_bounds__(256) void kl_finish(const float* __restrict__ partials,
                                                 const int n,
                                                 float* __restrict__ out) {
    __shared__ double red[256];
    const int t = threadIdx.x;
    double sums[3];
    for (int v = 0; v < 3; v++) {
        double a = 0.0;
        for (int i = t; i < n; i += 256) a += (double)partials[v * n + i];
        red[t] = a;
        __syncthreads();
        for (int s = 128; s > 0; s >>= 1) {
            if (t < s) red[t] += red[t + s];
            __syncthreads();
        }
        sums[v] = red[0];
        __syncthreads();
    }
    if (t == 0) {
        const double mean_log = sums[0] / 16777216.0;
        const double mean_sp  = sums[1] / 16777216.0;
        const double kl = -0.5 * (4096.0 * mean_log - sums[2] - 4096.0 * mean_sp);
        out[0] = (float)kl;
    }
}

// ---------------------------------------------------------------------------
// Fallback (only if ws too small): naive fp32 dual GEMM + partials.
// ---------------------------------------------------------------------------
__global__ void fb_partials(const float* __restrict__ wmu,
                            const float* __restrict__ wsg,
                            float* __restrict__ partials) {
    __shared__ float red[256];
    const int t = threadIdx.x;
    float s_abs = 0.f, s_sp = 0.f, s_log = 0.f;
    for (int i = blockIdx.x * 256 + t; i < NELEM; i += 1024 * 256) {
        s_abs += fabsf(wmu[i]);
        const float sp = softplus_fast(wsg[i]);
        s_sp += sp;
        s_log += __logf(sp);
    }
    float vals[3] = { s_log, s_sp, s_abs };
    for (int v = 0; v < 3; v++) {
        __syncthreads();
        red[t] = vals[v];
        __syncthreads();
        for (int s = 128; s > 0; s >>= 1) {
            if (t < s) red[t] += red[t + s];
            __syncthreads();
        }
        if (t == 0) partials[v * 1024 + blockIdx.x] = red[0];
    }
}

__global__ void fb_gemm(const float* __restrict__ A,
                        const float* __restrict__ Wm,
                        const float* __restrict__ Ws,
                        const float* __restrict__ bmu,
                        const float* __restrict__ bsg,
                        float* __restrict__ Cmu,
                        float* __restrict__ Csg) {
    __shared__ float As_[16][17], Bm[16][17], Bs_[16][17];
    const int tx = threadIdx.x, ty = threadIdx.y;
    const int row = blockIdx.y * 16 + ty;
    const int col = blockIdx.x * 16 + tx;
    float am = 0.f, as = 0.f;
    for (int k0 = 0; k0 < K_IN; k0 += 16) {
        As_[ty][tx] = A[(size_t)row * K_IN + k0 + tx];
        Bm[ty][tx]  = Wm[(size_t)(k0 + ty) * N_OUT + col];
        Bs_[ty][tx] = softplus_fast(Ws[(size_t)(k0 + ty) * N_OUT + col]);
        __syncthreads();
#pragma unroll
        for (int kk = 0; kk < 16; kk++) {
            const float av = As_[ty][kk];
            am += av * Bm[kk][tx];
            as += av * av * Bs_[kk][tx];
        }
        __syncthreads();
    }
    Cmu[(size_t)row * N_OUT + col] = am + bmu[col];
    Csg[(size_t)row * N_OUT + col] = as + softplus_fast(bsg[col]);
}

// ---------------------------------------------------------------------------
extern "C" void kernel_launch(void* const* d_in, const int* in_sizes, int n_in,
                              void* d_out, int out_size, void* d_ws, size_t ws_size,
                              hipStream_t stream) {
    const float* mu_in   = (const float*)d_in[0];
    // d_in[1] (sigma_in) unused by the reference
    const float* w_mu    = (const float*)d_in[2];
    const float* w_sigma = (const float*)d_in[3];
    const float* b_mu    = (const float*)d_in[4];
    const float* b_sigma = (const float*)d_in[5];

    float* out_mu  = (float*)d_out;
    float* out_sig = out_mu + (size_t)NELEM;
    float* out_kl  = out_mu + 2 * (size_t)NELEM;

    const size_t mat  = (size_t)NELEM;
    const size_t need = mat * 2 * 4 /* 4 bf16 matrices */ + 3 * 4096 * sizeof(float);

    if (ws_size >= need) {
        bf16* A      = (bf16*)d_ws;
        bf16* A2     = A + mat;
        bf16* Wmu_t  = A2 + mat;
        bf16* Wsg_t  = Wmu_t + mat;
        float* parts = (float*)(Wsg_t + mat);

        prep_all<<<2048 + 8192, 256, 0, stream>>>(
            w_mu, w_sigma, Wmu_t, Wsg_t, parts,
            (const float4*)mu_in, (u16x8*)A, (u16x8*)A2);
        gemm_bf16<<<dim3(16, 16, 2), 512, 0, stream>>>(
            A, Wmu_t, b_mu, out_mu, A2, Wsg_t, b_sigma, out_sig);
        kl_finish<<<1, 256, 0, stream>>>(parts, 2048, out_kl);
    } else {
        // emergency fallback: slow but correct fp32 path (needs 12KB ws)
        float* parts = (float*)d_ws;
        fb_partials<<<1024, 256, 0, stream>>>(w_mu, w_sigma, parts);
        fb_gemm<<<dim3(256, 256), dim3(16, 16), 0, stream>>>(
            mu_in, w_mu, w_sigma, b_mu, b_sigma, out_mu, out_sig);
        kl_finish<<<1, 256, 0, stream>>>(parts, 1024, out_kl);
    }
}

// Round 12
// 552.745 us; speedup vs baseline: 1.0147x; 1.0147x over previous
//
#include <hip/hip_runtime.h>
#include <hip/hip_bf16.h>
#include <math.h>

#define M_BATCH   4096
#define K_IN      4096
#define N_OUT     4096
#define NELEM     16777216   // 4096*4096

typedef __bf16 bf16;
typedef bf16  bf16x8 __attribute__((ext_vector_type(8)));
typedef float f32x4  __attribute__((ext_vector_type(4)));
typedef float f32x16 __attribute__((ext_vector_type(16)));
typedef unsigned short u16;
typedef u16 u16x8 __attribute__((ext_vector_type(8)));

// fast softplus: hardware v_exp/v_log, poly for small e (w_sigma in [-12,-2.2])
__device__ __forceinline__ float softplus_fast(float x) {
    if (x > 15.f) return x;
    const float e = __expf(x);
    if (e < 0.0883f)  // log1p(e) = e - e^2/2 + e^3/3, trunc err < 2e-6 rel
        return e * (1.f + e * (-0.5f + e * 0.3333333f));
    return __logf(1.f + e);
}

__device__ __forceinline__ unsigned short f2bf_bits(float x) {
    bf16 b = (bf16)x;
    return __builtin_bit_cast(unsigned short, b);
}

// async global->LDS, 16B per lane. LDS dst must be wave-uniform base + lane*16.
__device__ __forceinline__ void gload_lds16(const void* g, void* l) {
    __builtin_amdgcn_global_load_lds(
        (__attribute__((address_space(1))) void*)g,
        (__attribute__((address_space(3))) void*)l,
        16, 0, 0);
}

// ---------------------------------------------------------------------------
// prep_all v2 (R6): ONE launch.
//   bid <  2048 : prep_w — 128(i) x 64(o) tiles, 256B-contiguous transposed
//                 stores, 16B/lane; KL partials via shfl_xor wave-reduce.
//   bid >= 2048 : prep_a — mu -> A, A2=mu^2 (bf16), 8 elems/thread, 16B stores.
// ---------------------------------------------------------------------------
__global__ __launch_bounds__(256) void prep_all(const float* __restrict__ wmu,
                                                const float* __restrict__ wsg,
                                                bf16* __restrict__ Wmu_t,
                                                bf16* __restrict__ Wsg_t,
                                                float* __restrict__ partials,
                                                const float4* __restrict__ mu,
                                                u16x8* __restrict__ A8,
                                                u16x8* __restrict__ A28) {
    __shared__ bf16 tmu[128][65];
    __shared__ bf16 tsg[128][65];
    __shared__ float wred[4][3];

    const int t   = threadIdx.x;
    const int bid = blockIdx.x;

    if (bid >= 2048) {                       // ---- prep_a part ----
        const int i = (bid - 2048) * 256 + t;        // u16x8-granule index
        const float4 v0 = mu[2 * i];
        const float4 v1 = mu[2 * i + 1];
        u16x8 a, a2;
        a[0] = f2bf_bits(v0.x); a[1] = f2bf_bits(v0.y);
        a[2] = f2bf_bits(v0.z); a[3] = f2bf_bits(v0.w);
        a[4] = f2bf_bits(v1.x); a[5] = f2bf_bits(v1.y);
        a[6] = f2bf_bits(v1.z); a[7] = f2bf_bits(v1.w);
        a2[0] = f2bf_bits(v0.x * v0.x); a2[1] = f2bf_bits(v0.y * v0.y);
        a2[2] = f2bf_bits(v0.z * v0.z); a2[3] = f2bf_bits(v0.w * v0.w);
        a2[4] = f2bf_bits(v1.x * v1.x); a2[5] = f2bf_bits(v1.y * v1.y);
        a2[6] = f2bf_bits(v1.z * v1.z); a2[7] = f2bf_bits(v1.w * v1.w);
        A8[i]  = a;
        A28[i] = a2;
        return;
    }

    // ---- prep_w part: 128(i) x 64(o) tile ----
    const int ti = bid >> 6;            // i (K) tile, 0..31  (128 rows each)
    const int tj = bid & 63;            // o (N) tile, 0..63  (64 cols each)
    const int r  = t >> 4;              // 0..15
    const int c4 = (t & 15) << 2;       // 0,4,..,60

    float s_abs = 0.f, s_sp = 0.f, s_log = 0.f;

    for (int rr = 0; rr < 128; rr += 16) {
        const int row = rr + r;
        const size_t goff = (size_t)(ti * 128 + row) * N_OUT + tj * 64 + c4;
        const float4 vm = *(const float4*)(wmu + goff);
        const float4 vs = *(const float4*)(wsg + goff);
        const float sp0 = softplus_fast(vs.x), sp1 = softplus_fast(vs.y);
        const float sp2 = softplus_fast(vs.z), sp3 = softplus_fast(vs.w);
        s_abs += fabsf(vm.x) + fabsf(vm.y) + fabsf(vm.z) + fabsf(vm.w);
        s_sp  += sp0 + sp1 + sp2 + sp3;
        s_log += __logf(sp0) + __logf(sp1) + __logf(sp2) + __logf(sp3);
        tmu[row][c4 + 0] = (bf16)vm.x; tmu[row][c4 + 1] = (bf16)vm.y;
        tmu[row][c4 + 2] = (bf16)vm.z; tmu[row][c4 + 3] = (bf16)vm.w;
        tsg[row][c4 + 0] = (bf16)sp0;  tsg[row][c4 + 1] = (bf16)sp1;
        tsg[row][c4 + 2] = (bf16)sp2;  tsg[row][c4 + 3] = (bf16)sp3;
    }
    __syncthreads();

    // transposed write: Wt[o][i] = tile[i][o]; 16 threads x 16 B = 256 B/row
#pragma unroll
    for (int p = 0; p < 4; ++p) {
        const int jj = p * 16 + (t >> 4);   // o within tile
        const int i0 = (t & 15) << 3;       // i chunk (8 elems)
        u16x8 om, os;
#pragma unroll
        for (int e = 0; e < 8; ++e) {
            om[e] = __builtin_bit_cast(unsigned short, tmu[i0 + e][jj]);
            os[e] = __builtin_bit_cast(unsigned short, tsg[i0 + e][jj]);
        }
        const size_t o = (size_t)(tj * 64 + jj) * K_IN + ti * 128 + i0;
        *(u16x8*)(Wmu_t + o) = om;
        *(u16x8*)(Wsg_t + o) = os;
    }

    // KL partials: shfl_xor wave-reduce, one LDS combine
    float v0 = s_log, v1 = s_sp, v2 = s_abs;
#pragma unroll
    for (int off = 32; off; off >>= 1) {
        v0 += __shfl_xor(v0, off, 64);
        v1 += __shfl_xor(v1, off, 64);
        v2 += __shfl_xor(v2, off, 64);
    }
    if ((t & 63) == 0) {
        wred[t >> 6][0] = v0; wred[t >> 6][1] = v1; wred[t >> 6][2] = v2;
    }
    __syncthreads();
    if (t == 0) {
        partials[0 * 2048 + bid] = wred[0][0] + wred[1][0] + wred[2][0] + wred[3][0];
        partials[1 * 2048 + bid] = wred[0][1] + wred[1][1] + wred[2][1] + wred[3][1];
        partials[2 * 2048 + bid] = wred[0][2] + wred[1][2] + wred[2][2] + wred[3][2];
    }
}

// ---------------------------------------------------------------------------
// gemm_bf16: C[M,N] = A[M,K](bf16) * Bt[N,K]^T(bf16) + bias  (fp32 out)
// FINAL = verified R6 configuration (gemm ~258us, absmax 0.25, total ~557us).
// Structure: 256x256 tile, BK=64, 8 waves (2M x 4N, 128x64/wave), 128 KiB
// dbuf LDS, 32x32x16 MFMA, flat [par][256][64] layout + 16B-chunk XOR
// swizzle (linear gload_lds dst + inverse-swizzled src, rule 21).
// Phase q = m-fragment q: 4 A ds_read_b128 (+8 B bulk at q0 — all B-par
// reads complete in phase 1, making the ph3/4 B-restage WAR safe via the
// end-ph2 barrier). R4 4-barrier skeleton: end-ph2/ph6 plain barrier,
// end-ph4/ph8 vmcnt(4)+barrier (counted: retires prev K-tile's 8 loads,
// keeps the 4 just-issued in flight). XCD 4x8 remap (FETCH -33%, R2).
//
// STRUCTURAL CEILING (why search stopped):
//  - Unified VGPR+AGPR pool (wave slots halve at 64/128/256 regs): this
//    wave = 128 AGPR acc + 116 VGPR ~ 244 -> 2 waves/SIMD, 1 block/CU.
//    4 waves/SIMD requires <=128 total -> <=64x64 out/wave -> >=33% more
//    LDS read traffic (panel sharing) — measured R8: -68%.
//  - Phase 1218 cyc = MFMA floor 515 + LDS ~375 + sync/latency; bounded
//    in-block mitigations all measured: R2 -16%, R3 0, R4 +4%, R7 0,
//    R9 -43% (B off LDS = L2 scatter), R10 WAR race.
//  - SQ_LDS_BANK_CONFLICT (2.5e7) proportional to ds_read_b128 count:
//    intrinsic 2-lane/bank cost, not a fixable conflict (R7/R9/R10).
//  - Remaining 1.5x to m201's 1563 TF = full co-designed fine-interleave
//    schedule; partial grafts failed 3x; not a bounded-risk edit.
// ---------------------------------------------------------------------------
#define MFMA32 __builtin_amdgcn_mfma_f32_32x32x16_bf16

__global__ __launch_bounds__(512, 2) void gemm_bf16(
    const bf16* __restrict__ A1,  const bf16* __restrict__ Bt1,
    const float* __restrict__ bias1, float* __restrict__ C1,
    const bf16* __restrict__ A2_, const bf16* __restrict__ Bt2,
    const float* __restrict__ bias2, float* __restrict__ C2) {

    __shared__ bf16 As[2 * 256 * 64];   // [par][row 256][k 64], 64 KiB
    __shared__ bf16 Bs[2 * 256 * 64];   // 64 KiB

    const int z = blockIdx.z;
    const bf16*  A    = z ? A2_   : A1;
    const bf16*  Bt   = z ? Bt2   : Bt1;
    const float* bias = z ? bias2 : bias1;
    float*       C    = z ? C2    : C1;

    const int t = threadIdx.x;
    // XCD-aware remap: each XCD gets a contiguous 4x8 block of the tile grid.
    const int id   = blockIdx.y * 16 + blockIdx.x;  // 0..255 per z-slice
    const int xcd  = id & 7, cc_ = id >> 3;
    const int rowBase = (((xcd >> 1) << 2) + (cc_ >> 3)) << 8;
    const int colBase = (((xcd & 1) << 3) + (cc_ & 7)) << 8;

    // ---- staging: gload_lds writes linear (t*16); source chunk
    // inverse-swizzled so reads can swizzle (rule 21).
    const int srow   = t >> 3;                  // 0..63 (row within 64-row slab)
    const int schunk = (t & 7) ^ (srow & 7);    // source 16B chunk within row
    const char* aG = (const char*)(A  + (size_t)(rowBase + srow) * K_IN + schunk * 8);
    const char* bG = (const char*)(Bt + (size_t)(colBase + srow) * K_IN + schunk * 8);
    char* aL = (char*)As + t * 16;
    char* bL = (char*)Bs + t * 16;

#define STAGE_A(kt, h, par) do {                                               \
        const size_t kb_ = (size_t)((kt) & 63) << 7;                           \
        gload_lds16(aG + kb_ + (size_t)(h) * (128 * K_IN * 2),                 \
                    aL + ((par) << 15) + ((h) << 14));                         \
        gload_lds16(aG + kb_ + (size_t)(h) * (128 * K_IN * 2) + 64 * K_IN * 2, \
                    aL + ((par) << 15) + ((h) << 14) + 8192);                  \
    } while (0)
#define STAGE_B(kt, h, par) do {                                               \
        const size_t kb_ = (size_t)((kt) & 63) << 7;                           \
        gload_lds16(bG + kb_ + (size_t)(h) * (128 * K_IN * 2),                 \
                    bL + ((par) << 15) + ((h) << 14));                         \
        gload_lds16(bG + kb_ + (size_t)(h) * (128 * K_IN * 2) + 64 * K_IN * 2, \
                    bL + ((par) << 15) + ((h) << 14) + 8192);                  \
    } while (0)

    // ---- fragment read addressing (32x32x16, flat 128B rows) ----
    const int lane = t & 63;
    const int wave = t >> 6;
    const int wr = wave >> 2;            // 0..1 : M half (128 rows)
    const int wc = wave & 3;             // 0..3 : N quarter (64 cols)
    const int fr = lane & 31;            // row within 32-row frag
    const int kh = lane >> 5;            // k-half (8 of 16 k per slice)
    int cS[4];                           // swizzled 16B-chunk byte offsets
#pragma unroll
    for (int s = 0; s < 4; ++s)
        cS[s] = (((s << 1) | kh) ^ (fr & 7)) << 4;
    const char* aRd = (const char*)As + ((wr << 7) + fr) * 128;
    const char* bRd = (const char*)Bs + ((wc << 6) + fr) * 128;

// Phase q = m-fragment q: 4 A ds_read_b128 (+8 B bulk at q0), 8 MFMA
// (2 n-frags x 4 k-slices, per-acc ks order 0..3).
// BAR: 0 = free-run, 1 = barrier after MFMA; VM: vmcnt(4) before barrier.
#define PHASE(par, q, STAGE_STMT, VM, BAR) do {                                \
        if ((q) == 0) {                                                        \
            _Pragma("unroll")                                                  \
            for (int n = 0; n < 2; ++n)                                        \
                _Pragma("unroll")                                              \
                for (int s = 0; s < 4; ++s)                                    \
                    bfrag[n][s] = *(const bf16x8*)(bRd + ((par) << 15)         \
                                                  + (n << 12) + cS[s]);        \
        }                                                                      \
        bf16x8 a_[4];                                                          \
        _Pragma("unroll")                                                      \
        for (int s = 0; s < 4; ++s)                                            \
            a_[s] = *(const bf16x8*)(aRd + ((par) << 15) + ((q) << 12) + cS[s]);\
        STAGE_STMT;                                                            \
        __builtin_amdgcn_s_setprio(1);                                         \
        _Pragma("unroll")                                                      \
        for (int s = 0; s < 4; ++s) {                                          \
            acc[q][0] = MFMA32(a_[s], bfrag[0][s], acc[q][0], 0, 0, 0);        \
            acc[q][1] = MFMA32(a_[s], bfrag[1][s], acc[q][1], 0, 0, 0);        \
        }                                                                      \
        __builtin_amdgcn_s_setprio(0);                                         \
        if (VM) {                                                              \
            asm volatile("s_waitcnt vmcnt(4)" ::: "memory");                   \
            __builtin_amdgcn_sched_barrier(0);                                 \
        }                                                                      \
        if (BAR) {                                                             \
            __builtin_amdgcn_sched_barrier(0);                                 \
            __builtin_amdgcn_s_barrier();                                      \
            __builtin_amdgcn_sched_barrier(0);                                 \
        }                                                                      \
    } while (0)

    f32x16 acc[4][2];
#pragma unroll
    for (int m = 0; m < 4; ++m)
#pragma unroll
        for (int n = 0; n < 2; ++n)
#pragma unroll
            for (int e = 0; e < 16; ++e) acc[m][n][e] = 0.f;

    // prologue: stage kt0 + kt1 fully (16 loads); retire kt0 (keep kt1 in flight)
    STAGE_A(0, 0, 0); STAGE_A(0, 1, 0);
    STAGE_B(0, 0, 0); STAGE_B(0, 1, 0);
    STAGE_A(1, 0, 1); STAGE_A(1, 1, 1);
    STAGE_B(1, 0, 1); STAGE_B(1, 1, 1);
    asm volatile("s_waitcnt vmcnt(8)" ::: "memory");
    __builtin_amdgcn_sched_barrier(0);
    __builtin_amdgcn_s_barrier();
    __builtin_amdgcn_sched_barrier(0);

    for (int i = 0; i < 32; ++i) {          // 2 K-tiles per iter, K = 64*64
        const int kA1 = 2 * i + 1;          // A(kt+1) -> par1 (restage noop i=0)
        const int kB0 = 2 * i + 2;          // B(kt+2) -> par0
        const int kA0 = 2 * i + 2;          // A(kt+2) -> par0
        const int kB1 = 2 * i + 3;          // B(kt+3) -> par1
        {   // phases 1-4: compute kt=2i from par0
            bf16x8 bfrag[2][4];
            PHASE(0, 0, STAGE_A(kA1, 0, 1), 0, 0);
            PHASE(0, 1, STAGE_A(kA1, 1, 1), 0, 1);   // end-ph2 barrier
            PHASE(0, 2, STAGE_B(kB0, 0, 0), 0, 0);
            PHASE(0, 3, STAGE_B(kB0, 1, 0), 1, 1);   // vmcnt(4) + end-ph4 barrier
        }
        {   // phases 5-8: compute kt=2i+1 from par1
            bf16x8 bfrag[2][4];
            PHASE(1, 0, STAGE_A(kA0, 0, 0), 0, 0);
            PHASE(1, 1, STAGE_A(kA0, 1, 0), 0, 1);   // end-ph6 barrier
            PHASE(1, 2, STAGE_B(kB1, 0, 1), 0, 0);
            PHASE(1, 3, STAGE_B(kB1, 1, 1), 1, 1);   // vmcnt(4) + end-ph8 barrier
        }
    }

    asm volatile("s_waitcnt vmcnt(0)" ::: "memory");  // drain tail junk loads

    // epilogue: 32x32 C/D layout col=lane&31, row=(reg&3)+8*(reg>>2)+4*kh
#pragma unroll
    for (int n = 0; n < 2; ++n) {
        const int c = colBase + (wc << 6) + (n << 5) + fr;
        float b = bias[c];
        if (z) b = softplus_fast(b);
#pragma unroll
        for (int m = 0; m < 4; ++m) {
            const int rb = rowBase + (wr << 7) + (m << 5) + (kh << 2);
#pragma unroll
            for (int reg = 0; reg < 16; ++reg) {
                const int row = rb + (reg & 3) + ((reg >> 2) << 3);
                C[(size_t)row * N_OUT + c] = acc[m][n][reg] + b;
            }
        }
    }
#undef STAGE_A
#undef STAGE_B
#undef PHASE
}

// ---------------------------------------------------------------------------
// kl_finish: reduce partials (3 x n) in double, write scalar kl.
// ---------------------------------------------------------------------------
__global__ __launch_bounds__(256) void kl_finish(const float* __restrict__ partials,
                                                 const int n,
                                                 float* __restrict__ out) {
    __shared__ double red[256];
    const int t = threadIdx.x;
    double sums[3];
    for (int v = 0; v < 3; v++) {
        double a = 0.0;
        for (int i = t; i < n; i += 256) a += (double)partials[v * n + i];
        red[t] = a;
        __syncthreads();
        for (int s = 128; s > 0; s >>= 1) {
            if (t < s) red[t] += red[t + s];
            __syncthreads();
        }
        sums[v] = red[0];
        __syncthreads();
    }
    if (t == 0) {
        const double mean_log = sums[0] / 16777216.0;
        const double mean_sp  = sums[1] / 16777216.0;
        const double kl = -0.5 * (4096.0 * mean_log - sums[2] - 4096.0 * mean_sp);
        out[0] = (float)kl;
    }
}

// ---------------------------------------------------------------------------
// Fallback (only if ws too small): naive fp32 dual GEMM + partials.
// ---------------------------------------------------------------------------
__global__ void fb_partials(const float* __restrict__ wmu,
                            const float* __restrict__ wsg,
                            float* __restrict__ partials) {
    __shared__ float red[256];
    const int t = threadIdx.x;
    float s_abs = 0.f, s_sp = 0.f, s_log = 0.f;
    for (int i = blockIdx.x * 256 + t; i < NELEM; i += 1024 * 256) {
        s_abs += fabsf(wmu[i]);
        const float sp = softplus_fast(wsg[i]);
        s_sp += sp;
        s_log += __logf(sp);
    }
    float vals[3] = { s_log, s_sp, s_abs };
    for (int v = 0; v < 3; v++) {
        __syncthreads();
        red[t] = vals[v];
        __syncthreads();
        for (int s = 128; s > 0; s >>= 1) {
            if (t < s) red[t] += red[t + s];
            __syncthreads();
        }
        if (t == 0) partials[v * 1024 + blockIdx.x] = red[0];
    }
}

__global__ void fb_gemm(const float* __restrict__ A,
                        const float* __restrict__ Wm,
                        const float* __restrict__ Ws,
                        const float* __restrict__ bmu,
                        const float* __restrict__ bsg,
                        float* __restrict__ Cmu,
                        float* __restrict__ Csg) {
    __shared__ float As_[16][17], Bm[16][17], Bs_[16][17];
    const int tx = threadIdx.x, ty = threadIdx.y;
    const int row = blockIdx.y * 16 + ty;
    const int col = blockIdx.x * 16 + tx;
    float am = 0.f, as = 0.f;
    for (int k0 = 0; k0 < K_IN; k0 += 16) {
        As_[ty][tx] = A[(size_t)row * K_IN + k0 + tx];
        Bm[ty][tx]  = Wm[(size_t)(k0 + ty) * N_OUT + col];
        Bs_[ty][tx] = softplus_fast(Ws[(size_t)(k0 + ty) * N_OUT + col]);
        __syncthreads();
#pragma unroll
        for (int kk = 0; kk < 16; kk++) {
            const float av = As_[ty][kk];
            am += av * Bm[kk][tx];
            as += av * av * Bs_[kk][tx];
        }
        __syncthreads();
    }
    Cmu[(size_t)row * N_OUT + col] = am + bmu[col];
    Csg[(size_t)row * N_OUT + col] = as + softplus_fast(bsg[col]);
}

// ---------------------------------------------------------------------------
extern "C" void kernel_launch(void* const* d_in, const int* in_sizes, int n_in,
                              void* d_out, int out_size, void* d_ws, size_t ws_size,
                              hipStream_t stream) {
    const float* mu_in   = (const float*)d_in[0];
    // d_in[1] (sigma_in) unused by the reference
    const float* w_mu    = (const float*)d_in[2];
    const float* w_sigma = (const float*)d_in[3];
    const float* b_mu    = (const float*)d_in[4];
    const float* b_sigma = (const float*)d_in[5];

    float* out_mu  = (float*)d_out;
    float* out_sig = out_mu + (size_t)NELEM;
    float* out_kl  = out_mu + 2 * (size_t)NELEM;

    const size_t mat  = (size_t)NELEM;
    const size_t need = mat * 2 * 4 /* 4 bf16 matrices */ + 3 * 4096 * sizeof(float);

    if (ws_size >= need) {
        bf16* A      = (bf16*)d_ws;
        bf16* A2     = A + mat;
        bf16* Wmu_t  = A2 + mat;
        bf16* Wsg_t  = Wmu_t + mat;
        float* parts = (float*)(Wsg_t + mat);

        prep_all<<<2048 + 8192, 256, 0, stream>>>(
            w_mu, w_sigma, Wmu_t, Wsg_t, parts,
            (const float4*)mu_in, (u16x8*)A, (u16x8*)A2);
        gemm_bf16<<<dim3(16, 16, 2), 512, 0, stream>>>(
            A, Wmu_t, b_mu, out_mu, A2, Wsg_t, b_sigma, out_sig);
        kl_finish<<<1, 256, 0, stream>>>(parts, 2048, out_kl);
    } else {
        // emergency fallback: slow but correct fp32 path (needs 12KB ws)
        float* parts = (float*)d_ws;
        fb_partials<<<1024, 256, 0, stream>>>(w_mu, w_sigma, parts);
        fb_gemm<<<dim3(256, 256), dim3(16, 16), 0, stream>>>(
            mu_in, w_mu, w_sigma, b_mu, b_sigma, out_mu, out_sig);
        kl_finish<<<1, 256, 0, stream>>>(parts, 1024, out_kl);
    }
}